// Round 6
// baseline (329.280 us; speedup 1.0000x reference)
//
#include <hip/hip_runtime.h>

// Problem constants
#define NN 100000      // nodes
#define NE 600000      // edges
#define D  128         // feature dim in (both layers)
#define DOUT2 96
#define NREL 4
#define KREL 512       // NREL * D
#define KCAT 640       // KREL + D

typedef short short8 __attribute__((ext_vector_type(8)));   // 8 bf16
typedef float f32x4  __attribute__((ext_vector_type(4)));

// fp32 -> bf16 round-to-nearest-even (finite inputs)
__device__ __forceinline__ ushort f2bf(float x) {
    unsigned u = __builtin_bit_cast(unsigned, x);
    u += 0x7fffu + ((u >> 16) & 1u);
    return (ushort)(u >> 16);
}
__device__ __forceinline__ float bfhi(unsigned u) {
    return __builtin_bit_cast(float, u & 0xffff0000u);
}
__device__ __forceinline__ float bflo(unsigned u) {
    return __builtin_bit_cast(float, u << 16);
}

// ---------------------------------------------------------------------------
// Fused prep: x->bf16 convert, pack Wcp1, pack Wcp2, count (dst,rel) degrees.
// cnt must be zeroed by the preceding memset dispatch.
__global__ void prep0(const float* __restrict__ x, ushort* __restrict__ Xb,
                      const float* __restrict__ W1, const float* __restrict__ root1,
                      short* __restrict__ Wp1,
                      const float* __restrict__ W2, const float* __restrict__ root2,
                      short* __restrict__ Wp2,
                      const int* __restrict__ dst, const int* __restrict__ et,
                      float* __restrict__ cnt) {
    int i = blockIdx.x * 256 + threadIdx.x;
    const int S2 = (NN * D) / 4;      // float4 -> ushort4 converts
    const int S3 = KCAT * D;          // pack W1 elements
    const int S4 = KCAT * DOUT2;      // pack W2 elements
    const int S5 = NE;                // degree-count atomics
    if (i < S2) {
        float4 v = ((const float4*)x)[i];
        ushort4 o;
        o.x = f2bf(v.x); o.y = f2bf(v.y); o.z = f2bf(v.z); o.w = f2bf(v.w);
        ((ushort4*)Xb)[i] = o;
        return;
    }
    i -= S2;
    if (i < S3) {   // Wcp[kq][n][j] = Wcat[kq*8+j][n], BN = 128
        int j = i & 7, rest = i >> 3;
        int n = rest % D, kq = rest / D;
        int k = kq * 8 + j;
        float v = (k < KREL) ? W1[(size_t)k * D + n] : root1[(size_t)(k - KREL) * D + n];
        Wp1[i] = (short)f2bf(v);
        return;
    }
    i -= S3;
    if (i < S4) {   // BN = 96
        int j = i & 7, rest = i >> 3;
        int n = rest % DOUT2, kq = rest / DOUT2;
        int k = kq * 8 + j;
        float v = (k < KREL) ? W2[(size_t)k * DOUT2 + n] : root2[(size_t)(k - KREL) * DOUT2 + n];
        Wp2[i] = (short)f2bf(v);
        return;
    }
    i -= S4;
    if (i < S5) {
        unsafeAtomicAdd(&cnt[dst[i] * NREL + et[i]], 1.0f);
        return;
    }
}

// ---------------------------------------------------------------------------
// Allocate bucket starts: start2[v*4+r] for the (v,r) CSR. Starts need not be
// node-ordered — block-local exclusive scan + one global cursor atomic/block.
__global__ __launch_bounds__(256) void alloc_start(
    const float* __restrict__ cnt, int* __restrict__ cursor,
    int* __restrict__ start2) {
    __shared__ int s[256];
    __shared__ int sbase;
    int tid = threadIdx.x;
    int v = blockIdx.x * 256 + tid;
    float4 c = (v < NN) ? *(const float4*)&cnt[(size_t)v * 4]
                        : make_float4(0.f, 0.f, 0.f, 0.f);
    int d0 = (int)c.x, d1 = (int)c.y, d2 = (int)c.z, d3 = (int)c.w;
    int deg = d0 + d1 + d2 + d3;
    s[tid] = deg; __syncthreads();
    for (int o = 1; o < 256; o <<= 1) {   // inclusive scan
        int t = (tid >= o) ? s[tid - o] : 0;
        __syncthreads();
        s[tid] += t;
        __syncthreads();
    }
    if (tid == 255) sbase = atomicAdd(cursor, s[255]);
    __syncthreads();
    if (v < NN) {
        int st = sbase + s[tid] - deg;    // exclusive prefix + block base
        int4 o;
        o.x = st; o.y = st + d0; o.z = o.y + d1; o.w = o.z + d2;
        *(int4*)&start2[(size_t)v * 4] = o;
    }
}

// ---------------------------------------------------------------------------
// Bucket edges by (dst, rel); store src node id.
__global__ void bucket2(const int* __restrict__ src, const int* __restrict__ dst,
                        const int* __restrict__ et, const int* __restrict__ start2,
                        int* __restrict__ fill2, int* __restrict__ srcn) {
    int e = blockIdx.x * blockDim.x + threadIdx.x;
    if (e >= NE) return;
    int idx = dst[e] * NREL + et[e];
    int pos = start2[idx] + atomicAdd(&fill2[idx], 1);
    srcn[pos] = src[e];
}

// ---------------------------------------------------------------------------
// Fused RGCN layer — 16-node tile, 256 threads (4 waves), 16 KB LDS,
// __launch_bounds__(256,8) -> 8 blocks/CU = 32 waves/CU.
//   Phase 1: 16 quarter-wave chains, one node each; 4 contiguous same-relation
//            runs per node; raw-sum accumulate into acc[8] (norm folded once
//            at run end); bf16 A-frag tile in LDS.
//   Phase 2: 16x640 @ 640xBN MFMA; wave w covers frag range
//            [(w*NF)/4, ((w+1)*NF)/4); B-frags from L2-resident packed Wcp;
//            root part (k>=512) read from the bf16 feature rows.
template <int BN, bool RELU, bool OUT_BF16>
__global__ __launch_bounds__(256, 8) void rgcn_fused(
    const ushort* __restrict__ Xb,    // [M,128] bf16
    const int*   __restrict__ srcn,   // [NE] bucketed by (dst,rel)
    const int*   __restrict__ start2, // [M*4] bucket starts
    const float* __restrict__ cnt,    // [M,4] bucket sizes
    const short* __restrict__ Wcp,    // [80][BN][8] bf16
    const float* __restrict__ bias,   // [BN]
    void*        __restrict__ Cout,   // [M,BN] bf16 or f32
    int M) {
    constexpr int NF = BN / 16;
    __shared__ short At[64 * 16 * 8];   // 16 KB: [kq16][node16][8]

    const int tid  = threadIdx.x;
    const int wave = tid >> 6;
    const int lane = tid & 63;
    const int l    = lane & 15;     // phase1: feat octet / phase2: m16
    const int qw   = lane >> 4;     // phase1: quarter / phase2: k-quad q
    const int g    = wave * 4 + qw; // chain/node slot 0..15
    const int v0   = blockIdx.x * 16;
    const int v    = v0 + g;        // NN % 16 == 0 -> always < M

    int4   st4 = *(const int4*)&start2[(size_t)v * 4];
    float4 c4  = *(const float4*)&cnt[(size_t)v * 4];
    const int   stv[4] = {st4.x, st4.y, st4.z, st4.w};
    const float cv[4]  = {c4.x, c4.y, c4.z, c4.w};

#define UNPACK_ADD(XB) {                                      \
        acc[0] += bflo(XB.x); acc[1] += bfhi(XB.x);           \
        acc[2] += bflo(XB.y); acc[3] += bfhi(XB.y);           \
        acc[4] += bflo(XB.z); acc[5] += bfhi(XB.z);           \
        acc[6] += bflo(XB.w); acc[7] += bfhi(XB.w); }

    // ---- phase 1: 4 same-relation runs, raw sums, norm folded at run end ----
#pragma unroll
    for (int r = 0; r < 4; r++) {
        float acc[8];
#pragma unroll
        for (int j = 0; j < 8; j++) acc[j] = 0.0f;
        int e = stv[r], end = e + (int)cv[r];
        for (; e + 1 < end; e += 2) {
            int s0 = srcn[e], s1 = srcn[e + 1];
            uint4 x0 = *(const uint4*)&Xb[(size_t)s0 * D + l * 8];
            uint4 x1 = *(const uint4*)&Xb[(size_t)s1 * D + l * 8];
            UNPACK_ADD(x0); UNPACK_ADD(x1);
        }
        if (e < end) {
            int s0 = srcn[e];
            uint4 x0 = *(const uint4*)&Xb[(size_t)s0 * D + l * 8];
            UNPACK_ADD(x0);
        }
        float nrm = 1.0f / fmaxf(cv[r], 1.0f);
        short8 w;
#pragma unroll
        for (int j = 0; j < 8; j++) w[j] = (short)f2bf(nrm * acc[j]);
        *(short8*)&At[((r * 16 + l) * 16 + g) * 8] = w;
    }
#undef UNPACK_ADD

    __syncthreads();

    // ---- phase 2: 16x640 @ 640xBN, frag range per wave ----
    const int m16  = l;
    const int q    = qw;
    const int base = (wave * NF) / 4;
    const bool two = (((wave + 1) * NF) / 4 - base) > 1;   // wave-uniform
    f32x4 a20 = (f32x4)0.0f, a21 = (f32x4)0.0f;

#pragma unroll 4
    for (int ks = 0; ks < 16; ks++) {
        short8 af = *(const short8*)&At[((ks * 4 + q) * 16 + m16) * 8];
        const short* bb = Wcp + ((size_t)(ks * 4 + q) * BN + base * 16 + m16) * 8;
        short8 b0 = *(const short8*)bb;
        a20 = __builtin_amdgcn_mfma_f32_16x16x32_bf16(af, b0, a20, 0, 0, 0);
        if (two) {
            short8 b1 = *(const short8*)(bb + 128);
            a21 = __builtin_amdgcn_mfma_f32_16x16x32_bf16(af, b1, a21, 0, 0, 0);
        }
    }
    {   // root part: k = 512..639 directly from bf16 feature rows
        const ushort* Xrow = Xb + (size_t)(v0 + m16) * D;
#pragma unroll
        for (int s2 = 0; s2 < 4; s2++) {
            short8 af = *(const short8*)&Xrow[s2 * 32 + q * 8];
            const short* bb = Wcp + ((size_t)((16 + s2) * 4 + q) * BN + base * 16 + m16) * 8;
            short8 b0 = *(const short8*)bb;
            a20 = __builtin_amdgcn_mfma_f32_16x16x32_bf16(af, b0, a20, 0, 0, 0);
            if (two) {
                short8 b1 = *(const short8*)(bb + 128);
                a21 = __builtin_amdgcn_mfma_f32_16x16x32_bf16(af, b1, a21, 0, 0, 0);
            }
        }
    }

    // ---- epilogue ----
    {
        int n0 = base * 16 + m16;
        float bs0 = bias[n0];
#pragma unroll
        for (int r = 0; r < 4; r++) {
            int m = v0 + q * 4 + r;
            float vv = a20[r] + bs0;
            if (RELU) vv = fmaxf(vv, 0.0f);
            if (OUT_BF16) ((ushort*)Cout)[(size_t)m * BN + n0] = f2bf(vv);
            else          ((float*)Cout)[(size_t)m * BN + n0]  = vv;
        }
        if (two) {
            int n1 = n0 + 16;
            float bs1 = bias[n1];
#pragma unroll
            for (int r = 0; r < 4; r++) {
                int m = v0 + q * 4 + r;
                float vv = a21[r] + bs1;
                if (RELU) vv = fmaxf(vv, 0.0f);
                if (OUT_BF16) ((ushort*)Cout)[(size_t)m * BN + n1] = f2bf(vv);
                else          ((float*)Cout)[(size_t)m * BN + n1]  = vv;
            }
        }
    }
}

// ---------------------------------------------------------------------------
extern "C" void kernel_launch(void* const* d_in, const int* in_sizes, int n_in,
                              void* d_out, int out_size, void* d_ws, size_t ws_size,
                              hipStream_t stream) {
    const float* x     = (const float*)d_in[0];
    const int*   ei    = (const int*)d_in[1];
    const int*   et    = (const int*)d_in[2];
    const float* W1    = (const float*)d_in[3];
    const float* root1 = (const float*)d_in[4];
    const float* b1    = (const float*)d_in[5];
    const float* W2    = (const float*)d_in[6];
    const float* root2 = (const float*)d_in[7];
    const float* b2    = (const float*)d_in[8];
    const int* srcp = ei;
    const int* dstp = ei + NE;
    float* out = (float*)d_out;

    // Workspace layout (all segments 16-B aligned)
    short*  Wp1   = (short*)d_ws;                          // 640*128 bf16
    short*  Wp2   = Wp1 + (size_t)KCAT * D;                // 640*96  bf16
    ushort* Xb    = (ushort*)(Wp2 + (size_t)KCAT * DOUT2); // NN*128 bf16
    ushort* h     = Xb + (size_t)NN * D;                   // NN*128 bf16
    float*  cnt   = (float*)(h + (size_t)NN * D);          // NN*4 f32
    int*    fill2 = (int*)(cnt + (size_t)NN * NREL);       // NN*4
    int*    cursor= fill2 + (size_t)NN * NREL;             // 1 (+3 pad)
    int*    start2= cursor + 4;                            // NN*4
    int*    srcn  = start2 + (size_t)NN * NREL;            // NE

    // ---- prep: 4 dispatches ----
    // one memset covers cnt + fill2 + cursor (contiguous)
    hipMemsetAsync(cnt, 0, ((size_t)NN * NREL * 2 + 4) * sizeof(float), stream);
    {
        const int S = (NN * D) / 4 + KCAT * D + KCAT * DOUT2 + NE;
        prep0<<<(S + 255) / 256, 256, 0, stream>>>(x, Xb, W1, root1, Wp1,
                                                   W2, root2, Wp2, dstp, et, cnt);
    }
    alloc_start<<<(NN + 255) / 256, 256, 0, stream>>>(cnt, cursor, start2);
    bucket2<<<(NE + 255) / 256, 256, 0, stream>>>(srcp, dstp, et, start2, fill2, srcn);

    const int fblocks = NN / 16;  // 6250 (exact)

    // ---- Layer 1: h = relu(agg(x) @ W1cat + b1), bf16 out ----
    rgcn_fused<128, true, true><<<fblocks, 256, 0, stream>>>(
        Xb, srcn, start2, cnt, Wp1, b1, h, NN);
    // ---- Layer 2: out = agg(h) @ W2cat + b2, f32 out ----
    rgcn_fused<96, false, false><<<fblocks, 256, 0, stream>>>(
        h, srcn, start2, cnt, Wp2, b2, out, NN);
}